// Round 18
// baseline (270.103 us; speedup 1.0000x reference)
//
#include <hip/hip_runtime.h>

#define NB 8
#define NC 19
#define HW (512*512)
#define NPIX (NB*HW)
#define HHW (HW/2)          // 131072
#define RANK 183500u        // max(100000, int(262144*0.7)), < n_pix-1
#define NBIN 4096
#define CAP  4096
#define OFFB 69696          // window-B shift (px): byte delta 0x44100 spreads slice bits

__device__ __forceinline__ unsigned fkey(float f) {
    unsigned b = __float_as_uint(f);
    return (b & 0x80000000u) ? ~b : (b | 0x80000000u);
}
__device__ __forceinline__ float finv(unsigned u) {
    unsigned b = (u & 0x80000000u) ? (u & 0x7fffffffu) : ~u;
    return __uint_as_float(b);
}
__device__ __forceinline__ int bin_of(float l) {
    int b = (int)((l + 1.0f) * 224.0f);
    return b < 0 ? 0 : (b > NBIN - 1 ? NBIN - 1 : b);
}
__device__ __forceinline__ unsigned umn(unsigned a, unsigned b) { return a < b ? a : b; }
__device__ __forceinline__ unsigned umx(unsigned a, unsigned b) { return a > b ? a : b; }

// ---------------- Kernel 1: CE losses (R15 core) + in-register presence ------
// Two slice-spread windows per thread, counted-vmcnt pipeline, asm-opaque
// scalar loads, batch from blockIdx only (SGPR bases). Targets are already in
// registers -> presence bitmap is ~free here (mbit + wave-OR + 1 atomicOr).
// R12's spill risk doesn't apply: scalar base is ~60 live regs (vs 90+ for
// the dwordx4 variant that spilled). Health signal: VGPR<=72, dur<=70us.
// Prologue: blocks 0..32 zero ghist+count+present.
__global__ __launch_bounds__(256) void losses_kernel(
    const float* __restrict__ logits, const int* __restrict__ targets,
    float* __restrict__ losses, unsigned* __restrict__ wszero,
    unsigned* __restrict__ present)
{
    const int blk = blockIdx.x, tid = threadIdx.x;
    if (blk < 33) {   // zero ghist (32768 u32) + count (8) + present (8)
        int j = blk * 1024 + tid * 4;
        if (j < 32784) *reinterpret_cast<uint4*>(wszero + j) = make_uint4(0u,0u,0u,0u);
    }
    const int b  = blk >> 9;                       // batch: blockIdx-only (uniform)
    const int r  = ((blk & 511) << 8) + tid;       // [0, HHW) — lane-varying
    const int rB = (r + OFFB) & (HHW - 1);
    const int pA = (b << 18) + r;
    const int pB = (b << 18) + HHW + rB;
    const float* cb = logits + (size_t)b * NC * HW;   // batch base (SGPR)
    const int*   tb = targets + (size_t)b * HW;
    const unsigned vA = (unsigned)(r * 4);
    const unsigned vB = (unsigned)((HHW + rB) * 4);

    int tA, tB;
    float xA[NC], xB[NC];
    asm volatile("global_load_dword %0, %1, %2" : "=v"(tA) : "v"(vA), "s"(tb));
    asm volatile("global_load_dword %0, %1, %2" : "=v"(tB) : "v"(vB), "s"(tb));
    #pragma unroll
    for (int c = 0; c < NC; ++c)
        asm volatile("global_load_dword %0, %1, %2"
                     : "=v"(xA[c]) : "v"(vA), "s"(cb + (size_t)c * HW));
    #pragma unroll
    for (int c = 0; c < NC; ++c)
        asm volatile("global_load_dword %0, %1, %2"
                     : "=v"(xB[c]) : "v"(vB), "s"(cb + (size_t)c * HW));

    asm volatile("s_waitcnt vmcnt(19)" ::: "memory");
    __builtin_amdgcn_sched_barrier(0);

    {   // ---- window A (FP chain bit-identical to rounds 1-15) ----
        float m = xA[0];
        #pragma unroll
        for (int c = 1; c < NC; ++c) m = fmaxf(m, xA[c]);
        float s = 0.f, et = 0.f;
        #pragma unroll
        for (int c = 0; c < NC; ++c) {
            float e = expf(xA[c] - m);
            s += e;
            if (c == tA) et = e;
        }
        losses[pA] = (tA >= 0 && tA < NC) ? -logf(et / s + 1e-7f) : 0.f;
    }

    __builtin_amdgcn_sched_barrier(0);
    asm volatile("s_waitcnt vmcnt(1)" ::: "memory");
    __builtin_amdgcn_sched_barrier(0);

    {   // ---- window B ----
        float m = xB[0];
        #pragma unroll
        for (int c = 1; c < NC; ++c) m = fmaxf(m, xB[c]);
        float s = 0.f, et = 0.f;
        #pragma unroll
        for (int c = 0; c < NC; ++c) {
            float e = expf(xB[c] - m);
            s += e;
            if (c == tB) et = e;
        }
        losses[pB] = (tB >= 0 && tB < NC) ? -logf(et / s + 1e-7f) : 0.f;
    }

    // presence: targets already in registers, x-arrays dead -> minimal pressure
    unsigned mbit = 0u;
    if (tA >= 0 && tA < NC) mbit |= 1u << tA;
    if (tB >= 0 && tB < NC) mbit |= 1u << tB;
    #pragma unroll
    for (int o = 1; o < 64; o <<= 1) mbit |= __shfl_xor(mbit, o);
    if ((tid & 63) == 0 && mbit) atomicOr(&present[b], mbit);
}

// ---------------- Kernel 2: per-batch 4096-bin histogram (losses only) ------
// Targets stream removed (presence now comes from losses_kernel): half the
// read volume of the R15 version.
__global__ __launch_bounds__(256) void hist_kernel(
    const float* __restrict__ losses, unsigned* __restrict__ ghist)
{
    __shared__ unsigned lh[NBIN];
    const int b = blockIdx.y;
    for (int j = threadIdx.x; j < NBIN; j += 256) lh[j] = 0;
    __syncthreads();
    const float4* L = reinterpret_cast<const float4*>(losses + (size_t)b * HW)
                      + (size_t)blockIdx.x * 1024;
    for (int j = threadIdx.x; j < 1024; j += 256) {
        float4 v = L[j];
        atomicAdd(&lh[bin_of(v.x)], 1u);
        atomicAdd(&lh[bin_of(v.y)], 1u);
        atomicAdd(&lh[bin_of(v.z)], 1u);
        atomicAdd(&lh[bin_of(v.w)], 1u);
    }
    __syncthreads();
    unsigned* gh = ghist + b * NBIN;
    for (int j = threadIdx.x; j < NBIN; j += 256) {
        unsigned v = lh[j];
        if (v) atomicAdd(&gh[j], v);
    }
}

// ---------------- Kernel 3: compact rank-bin elems (parallel pick prologue) --
__global__ __launch_bounds__(256) void compact_kernel(
    const float* __restrict__ losses, const unsigned* __restrict__ ghist,
    unsigned* __restrict__ count, float* __restrict__ cand,
    unsigned* __restrict__ info)
{
    __shared__ unsigned wsum[4], woff[4];
    __shared__ unsigned sh_T, sh_r;
    const int b = blockIdx.y;
    const int tid = threadIdx.x;
    const int lane = tid & 63, wid = tid >> 6;
    const unsigned* gh = ghist + b * NBIN;

    unsigned s = 0;
    #pragma unroll
    for (int j = 0; j < 16; ++j) s += gh[tid * 16 + j];
    unsigned incl = s;
    #pragma unroll
    for (int o = 1; o < 64; o <<= 1) {
        unsigned v = (unsigned)__shfl_up((int)incl, o);
        if (lane >= o) incl += v;
    }
    if (lane == 63) wsum[wid] = incl;
    __syncthreads();
    if (tid == 0) { unsigned c = 0; for (int w = 0; w < 4; ++w) { woff[w] = c; c += wsum[w]; } }
    __syncthreads();
    unsigned excl = woff[wid] + incl - s;
    if (RANK >= excl && RANK < excl + s) {   // exactly one thread
        unsigned rr = RANK - excl, cum = 0;
        for (int j = 0; j < 16; ++j) {
            unsigned c = gh[tid * 16 + j];
            if (cum + c > rr) {
                sh_T = (unsigned)(tid * 16 + j); sh_r = rr - cum;
                if (blockIdx.x == 0) { info[b * 2] = sh_T; info[b * 2 + 1] = sh_r; }
                break;
            }
            cum += c;
        }
    }
    __syncthreads();
    const int T = (int)sh_T;

    const float4* L = reinterpret_cast<const float4*>(losses + (size_t)b * HW)
                      + (size_t)blockIdx.x * 1024;
    for (int j = tid; j < 1024; j += 256) {
        float4 v = L[j];
        float vals[4] = {v.x, v.y, v.z, v.w};
        #pragma unroll
        for (int q = 0; q < 4; ++q) {
            float val = vals[q];
            bool sel = (bin_of(val) == T);
            unsigned long long msk = __ballot(sel);
            if (msk) {
                int leader = __ffsll(msk) - 1;
                int pre = __popcll(msk & ((1ull << lane) - 1ull));
                unsigned base = 0;
                if (lane == leader) base = atomicAdd(&count[b], (unsigned)__popcll(msk));
                base = (unsigned)__shfl((int)base, leader);
                if (sel) {
                    unsigned idx = base + (unsigned)pre;
                    if (idx < CAP) cand[b * CAP + idx] = val;
                }
            }
        }
    }
}

// ---------------- Kernel 4: exact tie-aware rank select (two-level) ---------
__global__ __launch_bounds__(256) void final_kernel(
    const float* __restrict__ cand, const unsigned* __restrict__ count,
    const unsigned* __restrict__ info, float* __restrict__ thresh)
{
    __shared__ unsigned kf[CAP];
    __shared__ unsigned h[512];
    __shared__ unsigned sub[2048];
    __shared__ unsigned red[8];
    __shared__ unsigned kmin_sh, shift_sh, sb_sh, r2_sh, cnt_sh;
    const int tid = threadIdx.x, b = blockIdx.x;
    unsigned k = count[b]; if (k > CAP) k = CAP;
    const unsigned r = info[b * 2 + 1];

    for (unsigned j = tid; j < k; j += 256) kf[j] = fkey(cand[b * CAP + j]);
    for (int j = tid; j < 512; j += 256) h[j] = 0;
    __syncthreads();

    unsigned lmin = 0xFFFFFFFFu, lmax = 0u;
    for (unsigned j = tid; j < k; j += 256) { unsigned v = kf[j]; lmin = umn(lmin, v); lmax = umx(lmax, v); }
    #pragma unroll
    for (int o = 1; o < 64; o <<= 1) {
        lmin = umn(lmin, (unsigned)__shfl_xor((int)lmin, o));
        lmax = umx(lmax, (unsigned)__shfl_xor((int)lmax, o));
    }
    if ((tid & 63) == 0) { red[tid >> 6] = lmin; red[4 + (tid >> 6)] = lmax; }
    __syncthreads();
    if (tid == 0) {
        unsigned mn = red[0], mx = red[4];
        for (int w = 1; w < 4; ++w) { mn = umn(mn, red[w]); mx = umx(mx, red[4 + w]); }
        unsigned spread = mx - mn;
        int bits = 32 - __clz((int)(spread | 1u));
        shift_sh = (unsigned)(bits > 9 ? bits - 9 : 0);   // (spread>>shift) < 512
        kmin_sh = mn;
        cnt_sh = 0;
    }
    __syncthreads();
    const unsigned kmin = kmin_sh, shift = shift_sh;
    for (unsigned j = tid; j < k; j += 256) atomicAdd(&h[(kf[j] - kmin) >> shift], 1u);
    __syncthreads();
    if (tid == 0) {
        unsigned cum = 0; int sb = 0;
        while (sb < 511 && cum + h[sb] <= r) { cum += h[sb]; ++sb; }
        sb_sh = (unsigned)sb; r2_sh = r - cum;
    }
    __syncthreads();
    const unsigned sb = sb_sh;
    for (unsigned j = tid; j < k; j += 256) {
        if (((kf[j] - kmin) >> shift) == sb) {
            unsigned idx = atomicAdd(&cnt_sh, 1u);
            if (idx < 2048) sub[idx] = kf[j];
        }
    }
    __syncthreads();
    const unsigned k2 = umn(cnt_sh, 2048u), r2 = r2_sh;
    for (unsigned e = tid; e < k2; e += 256) {
        unsigned v = sub[e], less = 0, eq = 0;
        for (unsigned j = 0; j < k2; ++j) { unsigned u = sub[j]; less += (u < v); eq += (u == v); }
        if (less <= r2 && r2 < less + eq) thresh[b] = finv(v);
    }
}

// ---------------- Kernel 5: losses -> selection flags (in place) ------------
__global__ __launch_bounds__(256) void emit_kernel(
    float* __restrict__ out, const float* __restrict__ thresh,
    const unsigned* __restrict__ present)
{
    int i4 = blockIdx.x * 256 + threadIdx.x;
    int i = i4 * 4;
    int b = i >> 18;
    int p = i & (HW - 1);
    float th = thresh[b];
    unsigned pm = present[b];
    float4 v = reinterpret_cast<float4*>(out)[i4];
    float4 o;
    o.x = ((v.x > th) || ((p + 0) < NC && ((pm >> (p + 0)) & 1u))) ? 1.f : 0.f;
    o.y = ((v.y > th) || ((p + 1) < NC && ((pm >> (p + 1)) & 1u))) ? 1.f : 0.f;
    o.z = ((v.z > th) || ((p + 2) < NC && ((pm >> (p + 2)) & 1u))) ? 1.f : 0.f;
    o.w = ((v.w > th) || ((p + 3) < NC && ((pm >> (p + 3)) & 1u))) ? 1.f : 0.f;
    reinterpret_cast<float4*>(out)[i4] = o;
}

extern "C" void kernel_launch(void* const* d_in, const int* in_sizes, int n_in,
                              void* d_out, int out_size, void* d_ws, size_t ws_size,
                              hipStream_t stream)
{
    const float* logits  = (const float*)d_in[0];
    const int*   targets = (const int*)d_in[1];
    float* out = (float*)d_out;   // doubles as the losses buffer (NPIX floats)

    // ws layout: [ghist 32768 u32][count 8][present 8][info 16][thresh 8][cand 8*4096 f32]
    char* ws = (char*)d_ws;
    unsigned* ghist   = (unsigned*)(ws);                 // 131072 B
    unsigned* count   = (unsigned*)(ws + 131072);
    unsigned* present = (unsigned*)(ws + 131104);
    unsigned* info    = (unsigned*)(ws + 131136);
    float*    thresh  = (float*)   (ws + 131200);
    float*    cand    = (float*)   (ws + 131232);

    // no memset: losses_kernel blocks 0..32 zero ghist+count+present

    losses_kernel<<<NPIX / 512, 256, 0, stream>>>(logits, targets, out, ghist, present);
    hist_kernel<<<dim3(64, NB), 256, 0, stream>>>(out, ghist);
    compact_kernel<<<dim3(64, NB), 256, 0, stream>>>(out, ghist, count, cand, info);
    final_kernel<<<NB, 256, 0, stream>>>(cand, count, info, thresh);
    emit_kernel<<<NPIX / 4 / 256, 256, 0, stream>>>(out, thresh, present);
}

// Round 19
// 105.974 us; speedup vs baseline: 2.5488x; 2.5488x over previous
//
#include <hip/hip_runtime.h>

#define NB 8
#define NC 19
#define HW (512*512)
#define NPIX (NB*HW)
#define HHW (HW/2)          // 131072
#define RANK 183500u        // max(100000, int(262144*0.7)), < n_pix-1
#define NBIN 4096
#define CAP  4096
#define OFFB 69696          // window-B shift (px): byte delta 0x44100 spreads slice bits

__device__ __forceinline__ unsigned fkey(float f) {
    unsigned b = __float_as_uint(f);
    return (b & 0x80000000u) ? ~b : (b | 0x80000000u);
}
__device__ __forceinline__ float finv(unsigned u) {
    unsigned b = (u & 0x80000000u) ? (u & 0x7fffffffu) : ~u;
    return __uint_as_float(b);
}
__device__ __forceinline__ int bin_of(float l) {
    int b = (int)((l + 1.0f) * 224.0f);
    return b < 0 ? 0 : (b > NBIN - 1 ? NBIN - 1 : b);
}
__device__ __forceinline__ unsigned umn(unsigned a, unsigned b) { return a < b ? a : b; }
__device__ __forceinline__ unsigned umx(unsigned a, unsigned b) { return a > b ? a : b; }

// ---------------- Kernel 1: CE losses, 2 slice-spread windows, pipelined -----
// R15 VERBATIM — measured best (106.2 us total, absmax 0). Do not perturb:
// the live-set sits on a codegen knife-edge (R10/R12/R18 all fell off it).
// Batch index from blockIdx ONLY (SGPR channel bases); asm-opaque scalar
// loads; counted-vmcnt A/B pipeline; per-pixel FP chain bit-identical to all
// passing rounds. Prologue: blocks 0..32 zero ghist+count+present.
__global__ __launch_bounds__(256) void losses_kernel(
    const float* __restrict__ logits, const int* __restrict__ targets,
    float* __restrict__ losses, unsigned* __restrict__ wszero)
{
    const int blk = blockIdx.x, tid = threadIdx.x;
    if (blk < 33) {   // zero ghist (32768 u32) + count (8) + present (8)
        int j = blk * 1024 + tid * 4;
        if (j < 32784) *reinterpret_cast<uint4*>(wszero + j) = make_uint4(0u,0u,0u,0u);
    }
    const int b  = blk >> 9;                       // batch: blockIdx-only (uniform)
    const int r  = ((blk & 511) << 8) + tid;       // [0, HHW) — lane-varying
    const int rB = (r + OFFB) & (HHW - 1);         // modular shift within second half
    const int pA = (b << 18) + r;                  // b*HW + r
    const int pB = (b << 18) + HHW + rB;
    const float* cb = logits + (size_t)b * NC * HW;   // batch base (SGPR)
    const int*   tb = targets + (size_t)b * HW;
    const unsigned vA = (unsigned)(r * 4);
    const unsigned vB = (unsigned)((HHW + rB) * 4);

    int tA, tB;
    float xA[NC], xB[NC];
    asm volatile("global_load_dword %0, %1, %2" : "=v"(tA) : "v"(vA), "s"(tb));
    asm volatile("global_load_dword %0, %1, %2" : "=v"(tB) : "v"(vB), "s"(tb));
    #pragma unroll
    for (int c = 0; c < NC; ++c)
        asm volatile("global_load_dword %0, %1, %2"
                     : "=v"(xA[c]) : "v"(vA), "s"(cb + (size_t)c * HW));
    #pragma unroll
    for (int c = 0; c < NC; ++c)
        asm volatile("global_load_dword %0, %1, %2"
                     : "=v"(xB[c]) : "v"(vB), "s"(cb + (size_t)c * HW));

    // wait: tA,tB + A's 19 done; B's 19 still in flight
    asm volatile("s_waitcnt vmcnt(19)" ::: "memory");
    __builtin_amdgcn_sched_barrier(0);

    {   // ---- window A ----
        float m = xA[0];
        #pragma unroll
        for (int c = 1; c < NC; ++c) m = fmaxf(m, xA[c]);
        float s = 0.f, et = 0.f;
        #pragma unroll
        for (int c = 0; c < NC; ++c) {
            float e = expf(xA[c] - m);
            s += e;
            if (c == tA) et = e;
        }
        losses[pA] = (tA >= 0 && tA < NC) ? -logf(et / s + 1e-7f) : 0.f;
    }

    __builtin_amdgcn_sched_barrier(0);
    asm volatile("s_waitcnt vmcnt(1)" ::: "memory");   // B's 19 done; A-store may linger
    __builtin_amdgcn_sched_barrier(0);

    {   // ---- window B ----
        float m = xB[0];
        #pragma unroll
        for (int c = 1; c < NC; ++c) m = fmaxf(m, xB[c]);
        float s = 0.f, et = 0.f;
        #pragma unroll
        for (int c = 0; c < NC; ++c) {
            float e = expf(xB[c] - m);
            s += e;
            if (c == tB) et = e;
        }
        losses[pB] = (tB >= 0 && tB < NC) ? -logf(et / s + 1e-7f) : 0.f;
    }
}

// ---------------- Kernel 2: per-batch 4096-bin histogram + presence ---------
// 64 blocks/batch, 512 total — measured-best tail config.
__global__ __launch_bounds__(256) void hist_kernel(
    const float* __restrict__ losses, const int* __restrict__ targets,
    unsigned* __restrict__ ghist, unsigned* __restrict__ present)
{
    __shared__ unsigned lh[NBIN];
    __shared__ unsigned pres;
    const int b = blockIdx.y;
    for (int j = threadIdx.x; j < NBIN; j += 256) lh[j] = 0;
    if (threadIdx.x == 0) pres = 0u;
    __syncthreads();
    const float4* L = reinterpret_cast<const float4*>(losses + (size_t)b * HW)
                      + (size_t)blockIdx.x * 1024;
    const int4* T = reinterpret_cast<const int4*>(targets + (size_t)b * HW)
                    + (size_t)blockIdx.x * 1024;
    unsigned bits = 0u;
    for (int j = threadIdx.x; j < 1024; j += 256) {
        float4 v = L[j];
        atomicAdd(&lh[bin_of(v.x)], 1u);
        atomicAdd(&lh[bin_of(v.y)], 1u);
        atomicAdd(&lh[bin_of(v.z)], 1u);
        atomicAdd(&lh[bin_of(v.w)], 1u);
        int4 tv = T[j];
        if (tv.x >= 0 && tv.x < NC) bits |= 1u << tv.x;
        if (tv.y >= 0 && tv.y < NC) bits |= 1u << tv.y;
        if (tv.z >= 0 && tv.z < NC) bits |= 1u << tv.z;
        if (tv.w >= 0 && tv.w < NC) bits |= 1u << tv.w;
    }
    #pragma unroll
    for (int o = 1; o < 64; o <<= 1) bits |= __shfl_xor(bits, o);
    if ((threadIdx.x & 63) == 0 && bits) atomicOr(&pres, bits);
    __syncthreads();
    unsigned* gh = ghist + b * NBIN;
    for (int j = threadIdx.x; j < NBIN; j += 256) {
        unsigned v = lh[j];
        if (v) atomicAdd(&gh[j], v);
    }
    if (threadIdx.x == 0 && pres) atomicOr(&present[b], pres);
}

// ---------------- Kernel 3: compact rank-bin elems (parallel pick prologue) --
__global__ __launch_bounds__(256) void compact_kernel(
    const float* __restrict__ losses, const unsigned* __restrict__ ghist,
    unsigned* __restrict__ count, float* __restrict__ cand,
    unsigned* __restrict__ info)
{
    __shared__ unsigned wsum[4], woff[4];
    __shared__ unsigned sh_T, sh_r;
    const int b = blockIdx.y;
    const int tid = threadIdx.x;
    const int lane = tid & 63, wid = tid >> 6;
    const unsigned* gh = ghist + b * NBIN;

    unsigned s = 0;
    #pragma unroll
    for (int j = 0; j < 16; ++j) s += gh[tid * 16 + j];
    unsigned incl = s;
    #pragma unroll
    for (int o = 1; o < 64; o <<= 1) {
        unsigned v = (unsigned)__shfl_up((int)incl, o);
        if (lane >= o) incl += v;
    }
    if (lane == 63) wsum[wid] = incl;
    __syncthreads();
    if (tid == 0) { unsigned c = 0; for (int w = 0; w < 4; ++w) { woff[w] = c; c += wsum[w]; } }
    __syncthreads();
    unsigned excl = woff[wid] + incl - s;
    if (RANK >= excl && RANK < excl + s) {   // exactly one thread
        unsigned rr = RANK - excl, cum = 0;
        for (int j = 0; j < 16; ++j) {
            unsigned c = gh[tid * 16 + j];
            if (cum + c > rr) {
                sh_T = (unsigned)(tid * 16 + j); sh_r = rr - cum;
                if (blockIdx.x == 0) { info[b * 2] = sh_T; info[b * 2 + 1] = sh_r; }
                break;
            }
            cum += c;
        }
    }
    __syncthreads();
    const int T = (int)sh_T;

    const float4* L = reinterpret_cast<const float4*>(losses + (size_t)b * HW)
                      + (size_t)blockIdx.x * 1024;
    for (int j = tid; j < 1024; j += 256) {
        float4 v = L[j];
        float vals[4] = {v.x, v.y, v.z, v.w};
        #pragma unroll
        for (int q = 0; q < 4; ++q) {
            float val = vals[q];
            bool sel = (bin_of(val) == T);
            unsigned long long msk = __ballot(sel);
            if (msk) {
                int leader = __ffsll(msk) - 1;
                int pre = __popcll(msk & ((1ull << lane) - 1ull));
                unsigned base = 0;
                if (lane == leader) base = atomicAdd(&count[b], (unsigned)__popcll(msk));
                base = (unsigned)__shfl((int)base, leader);
                if (sel) {
                    unsigned idx = base + (unsigned)pre;
                    if (idx < CAP) cand[b * CAP + idx] = val;
                }
            }
        }
    }
}

// ---------------- Kernel 4: exact tie-aware rank select (two-level) ---------
__global__ __launch_bounds__(256) void final_kernel(
    const float* __restrict__ cand, const unsigned* __restrict__ count,
    const unsigned* __restrict__ info, float* __restrict__ thresh)
{
    __shared__ unsigned kf[CAP];
    __shared__ unsigned h[512];
    __shared__ unsigned sub[2048];
    __shared__ unsigned red[8];
    __shared__ unsigned kmin_sh, shift_sh, sb_sh, r2_sh, cnt_sh;
    const int tid = threadIdx.x, b = blockIdx.x;
    unsigned k = count[b]; if (k > CAP) k = CAP;
    const unsigned r = info[b * 2 + 1];

    for (unsigned j = tid; j < k; j += 256) kf[j] = fkey(cand[b * CAP + j]);
    for (int j = tid; j < 512; j += 256) h[j] = 0;
    __syncthreads();

    unsigned lmin = 0xFFFFFFFFu, lmax = 0u;
    for (unsigned j = tid; j < k; j += 256) { unsigned v = kf[j]; lmin = umn(lmin, v); lmax = umx(lmax, v); }
    #pragma unroll
    for (int o = 1; o < 64; o <<= 1) {
        lmin = umn(lmin, (unsigned)__shfl_xor((int)lmin, o));
        lmax = umx(lmax, (unsigned)__shfl_xor((int)lmax, o));
    }
    if ((tid & 63) == 0) { red[tid >> 6] = lmin; red[4 + (tid >> 6)] = lmax; }
    __syncthreads();
    if (tid == 0) {
        unsigned mn = red[0], mx = red[4];
        for (int w = 1; w < 4; ++w) { mn = umn(mn, red[w]); mx = umx(mx, red[4 + w]); }
        unsigned spread = mx - mn;
        int bits = 32 - __clz((int)(spread | 1u));
        shift_sh = (unsigned)(bits > 9 ? bits - 9 : 0);   // (spread>>shift) < 512
        kmin_sh = mn;
        cnt_sh = 0;
    }
    __syncthreads();
    const unsigned kmin = kmin_sh, shift = shift_sh;
    for (unsigned j = tid; j < k; j += 256) atomicAdd(&h[(kf[j] - kmin) >> shift], 1u);
    __syncthreads();
    if (tid == 0) {
        unsigned cum = 0; int sb = 0;
        while (sb < 511 && cum + h[sb] <= r) { cum += h[sb]; ++sb; }
        sb_sh = (unsigned)sb; r2_sh = r - cum;
    }
    __syncthreads();
    const unsigned sb = sb_sh;
    for (unsigned j = tid; j < k; j += 256) {
        if (((kf[j] - kmin) >> shift) == sb) {
            unsigned idx = atomicAdd(&cnt_sh, 1u);
            if (idx < 2048) sub[idx] = kf[j];
        }
    }
    __syncthreads();
    const unsigned k2 = umn(cnt_sh, 2048u), r2 = r2_sh;
    for (unsigned e = tid; e < k2; e += 256) {
        unsigned v = sub[e], less = 0, eq = 0;
        for (unsigned j = 0; j < k2; ++j) { unsigned u = sub[j]; less += (u < v); eq += (u == v); }
        if (less <= r2 && r2 < less + eq) thresh[b] = finv(v);
    }
}

// ---------------- Kernel 5: losses -> selection flags (in place) ------------
__global__ __launch_bounds__(256) void emit_kernel(
    float* __restrict__ out, const float* __restrict__ thresh,
    const unsigned* __restrict__ present)
{
    int i4 = blockIdx.x * 256 + threadIdx.x;
    int i = i4 * 4;
    int b = i >> 18;
    int p = i & (HW - 1);
    float th = thresh[b];
    unsigned pm = present[b];
    float4 v = reinterpret_cast<float4*>(out)[i4];
    float4 o;
    o.x = ((v.x > th) || ((p + 0) < NC && ((pm >> (p + 0)) & 1u))) ? 1.f : 0.f;
    o.y = ((v.y > th) || ((p + 1) < NC && ((pm >> (p + 1)) & 1u))) ? 1.f : 0.f;
    o.z = ((v.z > th) || ((p + 2) < NC && ((pm >> (p + 2)) & 1u))) ? 1.f : 0.f;
    o.w = ((v.w > th) || ((p + 3) < NC && ((pm >> (p + 3)) & 1u))) ? 1.f : 0.f;
    reinterpret_cast<float4*>(out)[i4] = o;
}

extern "C" void kernel_launch(void* const* d_in, const int* in_sizes, int n_in,
                              void* d_out, int out_size, void* d_ws, size_t ws_size,
                              hipStream_t stream)
{
    const float* logits  = (const float*)d_in[0];
    const int*   targets = (const int*)d_in[1];
    float* out = (float*)d_out;   // doubles as the losses buffer (NPIX floats)

    // ws layout: [ghist 32768 u32][count 8][present 8][info 16][thresh 8][cand 8*4096 f32]
    char* ws = (char*)d_ws;
    unsigned* ghist   = (unsigned*)(ws);                 // 131072 B
    unsigned* count   = (unsigned*)(ws + 131072);
    unsigned* present = (unsigned*)(ws + 131104);
    unsigned* info    = (unsigned*)(ws + 131136);
    float*    thresh  = (float*)   (ws + 131200);
    float*    cand    = (float*)   (ws + 131232);

    // no memset: losses_kernel blocks 0..32 zero ghist+count+present
    // (all consumed only by later dispatches — no intra-kernel race)

    losses_kernel<<<NPIX / 512, 256, 0, stream>>>(logits, targets, out, ghist);
    hist_kernel<<<dim3(64, NB), 256, 0, stream>>>(out, targets, ghist, present);
    compact_kernel<<<dim3(64, NB), 256, 0, stream>>>(out, ghist, count, cand, info);
    final_kernel<<<NB, 256, 0, stream>>>(cand, count, info, thresh);
    emit_kernel<<<NPIX / 4 / 256, 256, 0, stream>>>(out, thresh, present);
}